// Round 6
// baseline (84.565 us; speedup 1.0000x reference)
//
#include <hip/hip_runtime.h>
#include <math.h>

#define W_DIM 256
#define H_DIM 256
#define VROWS 16                      // output rows per thread
#define TY    4                       // waves per block
#define TILE_ROWS (VROWS * TY)        // 64 output rows per block
#define N_TILES (H_DIM / TILE_ROWS)   // 4 tiles per image
#define NROWS (VROWS + 2)             // rows loaded per thread

typedef float f32x4 __attribute__((ext_vector_type(4)));  // native vec for NT store

__device__ __forceinline__ void hmins(float4 vr, int lane, float4& h3, float4& hs) {
    float lf = __shfl_up(vr.w, 1);     // lane i-1's last element
    if (lane == 0) lf = INFINITY;
    float rf = __shfl_down(vr.x, 1);   // lane i+1's first element
    if (lane == 63) rf = INFINITY;

    hs.x = fminf(lf,   vr.y);
    hs.y = fminf(vr.x, vr.z);
    hs.z = fminf(vr.y, vr.w);
    hs.w = fminf(vr.z, rf);
    h3.x = fminf(hs.x, vr.x);
    h3.y = fminf(hs.y, vr.y);
    h3.z = fminf(hs.z, vr.z);
    h3.w = fminf(hs.w, vr.w);
}

__global__ __launch_bounds__(256) void MinValues_kernel(const float* __restrict__ x,
                                                        float* __restrict__ out,
                                                        int nwg) {
    // Bijective XCD swizzle (nwg % 8 == 0): consecutive work-ids share an XCD
    // so vertically adjacent tiles reuse halo rows in that XCD's L2.
    const int bid = blockIdx.x;
    const int wg  = (bid & 7) * (nwg >> 3) + (bid >> 3);

    const int img  = wg >> 2;              // wg / N_TILES
    const int tile = wg & (N_TILES - 1);

    const int lane = threadIdx.x;          // 0..63, 4 floats each along W
    const int ty   = threadIdx.y;          // 0..3
    const int i0   = tile * TILE_ROWS + ty * VROWS;

    const float* base = x + (size_t)img * (H_DIM * W_DIM) + lane * 4;

    // ---- Phase 1: issue ALL 18 row loads back-to-back (MLP=18) ----
    float4 v[NROWS];
    bool oob[NROWS];                       // wave-uniform -> scalar masks
#pragma unroll
    for (int r = 0; r < NROWS; ++r) {
        int row = i0 - 1 + r;
        oob[r] = (row < 0) | (row >= H_DIM);
        int rc = row < 0 ? 0 : (row > H_DIM - 1 ? H_DIM - 1 : row);
        v[r] = *reinterpret_cast<const float4*>(base + (size_t)rc * W_DIM);
    }

    // ---- Phase 2: rolling 3-row window (caps live h-registers) ----
    float* obase = out + (size_t)img * (H_DIM * W_DIM) + (size_t)i0 * W_DIM + lane * 4;

    const float4 VINF = make_float4(INFINITY, INFINITY, INFINITY, INFINITY);
    float4 h3_t, hs_t, h3_m, hs_m;
    hmins(oob[0] ? VINF : v[0], lane, h3_t, hs_t);
    hmins(oob[1] ? VINF : v[1], lane, h3_m, hs_m);

#pragma unroll
    for (int k = 0; k < VROWS; ++k) {
        float4 h3_b, hs_b;
        hmins(oob[k + 2] ? VINF : v[k + 2], lane, h3_b, hs_b);

        f32x4 o;
        o.x = fminf(fminf(h3_t.x, hs_m.x), h3_b.x);
        o.y = fminf(fminf(h3_t.y, hs_m.y), h3_b.y);
        o.z = fminf(fminf(h3_t.z, hs_m.z), h3_b.z);
        o.w = fminf(fminf(h3_t.w, hs_m.w), h3_b.w);

        // Output is never re-read: NT store keeps it from evicting input in L2/L3.
        __builtin_nontemporal_store(o, reinterpret_cast<f32x4*>(obase + (size_t)k * W_DIM));

        h3_t = h3_m;
        h3_m = h3_b;
        hs_m = hs_b;
    }
}

extern "C" void kernel_launch(void* const* d_in, const int* in_sizes, int n_in,
                              void* d_out, int out_size, void* d_ws, size_t ws_size,
                              hipStream_t stream) {
    const float* x = (const float*)d_in[0];
    float* out = (float*)d_out;

    const int total  = in_sizes[0];                 // N*C*H*W
    const int n_imgs = total / (H_DIM * W_DIM);     // 1024
    const int nwg    = n_imgs * N_TILES;            // 4096

    dim3 block(64, TY);                             // 256 threads
    MinValues_kernel<<<dim3(nwg), block, 0, stream>>>(x, out, nwg);
}

// Round 7
// 77.795 us; speedup vs baseline: 1.0870x; 1.0870x over previous
//
#include <hip/hip_runtime.h>
#include <math.h>

#define W_DIM 256
#define H_DIM 256
#define VROWS 8                       // output rows per thread
#define TY    4                       // waves per block
#define TILE_ROWS (VROWS * TY)        // 32 output rows per block
#define N_TILES (H_DIM / TILE_ROWS)   // 8 tiles per image
#define NROWS (VROWS + 2)             // rows loaded per thread

typedef float f32x4 __attribute__((ext_vector_type(4)));  // native vec for NT store

__device__ __forceinline__ void hmins(float4 vr, int lane, float4& h3, float4& hs) {
    float lf = __shfl_up(vr.w, 1);     // lane i-1's last element
    if (lane == 0) lf = INFINITY;
    float rf = __shfl_down(vr.x, 1);   // lane i+1's first element
    if (lane == 63) rf = INFINITY;

    hs.x = fminf(lf,   vr.y);
    hs.y = fminf(vr.x, vr.z);
    hs.z = fminf(vr.y, vr.w);
    hs.w = fminf(vr.z, rf);
    h3.x = fminf(hs.x, vr.x);
    h3.y = fminf(hs.y, vr.y);
    h3.z = fminf(hs.z, vr.z);
    h3.w = fminf(hs.w, vr.w);
}

__global__ __launch_bounds__(256) void MinValues_kernel(const float* __restrict__ x,
                                                        float* __restrict__ out,
                                                        int nwg) {
    // Bijective XCD swizzle (nwg % 8 == 0): consecutive work-ids share an XCD
    // so vertically adjacent tiles reuse halo rows in that XCD's L2.
    const int bid = blockIdx.x;
    const int wg  = (bid & 7) * (nwg >> 3) + (bid >> 3);

    const int img  = wg >> 3;              // wg / N_TILES
    const int tile = wg & (N_TILES - 1);

    const int lane = threadIdx.x;          // 0..63, 4 floats each along W
    const int ty   = threadIdx.y;          // 0..3
    const int i0   = tile * TILE_ROWS + ty * VROWS;

    const float* base = x + (size_t)img * (H_DIM * W_DIM) + lane * 4;

    // ---- Phase 1: issue ALL 10 row loads back-to-back (MLP=10) ----
    float4 v[NROWS];
    bool oob[NROWS];
#pragma unroll
    for (int r = 0; r < NROWS; ++r) {
        int row = i0 - 1 + r;
        oob[r] = (row < 0) | (row >= H_DIM);
        int rc = row < 0 ? 0 : (row > H_DIM - 1 ? H_DIM - 1 : row);
        v[r] = *reinterpret_cast<const float4*>(base + (size_t)rc * W_DIM);
    }
    // Scheduling fence: stop the compiler from sinking loads into the
    // consumption loop (R6 showed it collapses MLP to save VGPRs).
    asm volatile("" ::: "memory");

    // ---- Phase 2: rolling 3-row window (caps live h-registers) ----
    float* obase = out + (size_t)img * (H_DIM * W_DIM) + (size_t)i0 * W_DIM + lane * 4;

    const float4 VINF = make_float4(INFINITY, INFINITY, INFINITY, INFINITY);
    float4 h3_t, hs_t, h3_m, hs_m;
    hmins(oob[0] ? VINF : v[0], lane, h3_t, hs_t);
    hmins(oob[1] ? VINF : v[1], lane, h3_m, hs_m);

#pragma unroll
    for (int k = 0; k < VROWS; ++k) {
        float4 h3_b, hs_b;
        hmins(oob[k + 2] ? VINF : v[k + 2], lane, h3_b, hs_b);

        f32x4 o;
        o.x = fminf(fminf(h3_t.x, hs_m.x), h3_b.x);
        o.y = fminf(fminf(h3_t.y, hs_m.y), h3_b.y);
        o.z = fminf(fminf(h3_t.z, hs_m.z), h3_b.z);
        o.w = fminf(fminf(h3_t.w, hs_m.w), h3_b.w);

        // Output is never re-read: NT store keeps it from evicting input in L2/L3.
        __builtin_nontemporal_store(o, reinterpret_cast<f32x4*>(obase + (size_t)k * W_DIM));

        h3_t = h3_m;
        h3_m = h3_b;
        hs_m = hs_b;
    }
}

extern "C" void kernel_launch(void* const* d_in, const int* in_sizes, int n_in,
                              void* d_out, int out_size, void* d_ws, size_t ws_size,
                              hipStream_t stream) {
    const float* x = (const float*)d_in[0];
    float* out = (float*)d_out;

    const int total  = in_sizes[0];                 // N*C*H*W
    const int n_imgs = total / (H_DIM * W_DIM);     // 1024
    const int nwg    = n_imgs * N_TILES;            // 8192

    dim3 block(64, TY);                             // 256 threads
    MinValues_kernel<<<dim3(nwg), block, 0, stream>>>(x, out, nwg);
}